// Round 15
// baseline (35981.842 us; speedup 1.0000x reference)
//
#include <hip/hip_runtime.h>
#include <hip/hip_bf16.h>
#include <math.h>
#include <stdint.h>

#define B 8
#define T 1024
#define D 1024
#define H 16
#define DH 64
#define NSTEPS 4

#define NCHAIN 8            // 8 independent chains of 1 batch row
#define NPAIR 4             // blocks serve chain pairs (c, c+4)
#define NBLK_CHAIN 128      // block positions per chain (512 blocks total)
#define DIMS_PER_BLK 8

#define FLAG_STRIDE 16      // flags 64B apart (own cache line each)
#define RED_PITCH 37        // redA pitch (coprime to 32 -> conflict-free cols)

typedef __attribute__((ext_vector_type(8))) short bhalf8;
typedef __attribute__((ext_vector_type(4))) float f32x4;

__device__ __forceinline__ float sigmoidf_(float x) { return 1.0f / (1.0f + expf(-x)); }

// bf16 round-to-nearest-even, returned in low 16 bits
__device__ __forceinline__ unsigned bf16rne(float f) {
    unsigned x = __float_as_uint(f);
    return (x + 0x7FFFu + ((x >> 16) & 1u)) >> 16;
}
// unpack u32 = bf0 | bf1<<16 into two f32
#define UNPK(u, f0, f1)                                                       \
    { f0 = __uint_as_float((u) << 16); f1 = __uint_as_float((u) & 0xFFFF0000u); }

// ---------------------------------------------------------------------------
// bf16 MFMA GEMM (proven R12/R13): C[M,N] = A[M,K] @ W[N,K]^T + bias[N].
// MODE 0: C[m*N+n]; MODE 1: qkv scatter to q/k/v [B*H, T, DH].
// ---------------------------------------------------------------------------
template <int MODE>
__global__ __launch_bounds__(256) void gemm_mfma(
    const float* __restrict__ A, const float* __restrict__ W,
    const float* __restrict__ bias, float* __restrict__ C,
    int M, int N, int K, int ldw, int koff,
    float* __restrict__ qb, float* __restrict__ kb, float* __restrict__ vb)
{
    __shared__ unsigned short Asm[128 * 32];
    __shared__ unsigned short Wsm[128 * 32];
    const int tid = threadIdx.x;
    const int m0 = blockIdx.x * 128, n0 = blockIdx.y * 128;
    const int lane = tid & 63, wave = tid >> 6;
    const int wm = (wave >> 1) * 64, wn = (wave & 1) * 64;
    const int sr = tid >> 1, sk = (tid & 1) * 16;

    f32x4 acc[4][4] = {};

    for (int k0 = 0; k0 < K; k0 += 32) {
        {
            const float* s = A + (size_t)(m0 + sr) * K + k0 + sk;
            float4 a0 = *(const float4*)(s);
            float4 a1 = *(const float4*)(s + 4);
            float4 a2 = *(const float4*)(s + 8);
            float4 a3 = *(const float4*)(s + 12);
            uint4 p0, p1;
            p0.x = bf16rne(a0.x) | (bf16rne(a0.y) << 16);
            p0.y = bf16rne(a0.z) | (bf16rne(a0.w) << 16);
            p0.z = bf16rne(a1.x) | (bf16rne(a1.y) << 16);
            p0.w = bf16rne(a1.z) | (bf16rne(a1.w) << 16);
            p1.x = bf16rne(a2.x) | (bf16rne(a2.y) << 16);
            p1.y = bf16rne(a2.z) | (bf16rne(a2.w) << 16);
            p1.z = bf16rne(a3.x) | (bf16rne(a3.y) << 16);
            p1.w = bf16rne(a3.z) | (bf16rne(a3.w) << 16);
            *(uint4*)&Asm[sr * 32 + sk]     = p0;
            *(uint4*)&Asm[sr * 32 + sk + 8] = p1;
        }
        {
            const float* s = W + (size_t)(n0 + sr) * ldw + koff + k0 + sk;
            float4 a0 = *(const float4*)(s);
            float4 a1 = *(const float4*)(s + 4);
            float4 a2 = *(const float4*)(s + 8);
            float4 a3 = *(const float4*)(s + 12);
            uint4 p0, p1;
            p0.x = bf16rne(a0.x) | (bf16rne(a0.y) << 16);
            p0.y = bf16rne(a0.z) | (bf16rne(a0.w) << 16);
            p0.z = bf16rne(a1.x) | (bf16rne(a1.y) << 16);
            p0.w = bf16rne(a1.z) | (bf16rne(a1.w) << 16);
            p1.x = bf16rne(a2.x) | (bf16rne(a2.y) << 16);
            p1.y = bf16rne(a2.z) | (bf16rne(a2.w) << 16);
            p1.z = bf16rne(a3.x) | (bf16rne(a3.y) << 16);
            p1.w = bf16rne(a3.z) | (bf16rne(a3.w) << 16);
            *(uint4*)&Wsm[sr * 32 + sk]     = p0;
            *(uint4*)&Wsm[sr * 32 + sk + 8] = p1;
        }
        __syncthreads();

        bhalf8 af[4], bf[4];
#pragma unroll
        for (int mi = 0; mi < 4; ++mi)
            af[mi] = *(const bhalf8*)&Asm[(wm + mi * 16 + (lane & 15)) * 32 +
                                          (lane >> 4) * 8];
#pragma unroll
        for (int ni = 0; ni < 4; ++ni)
            bf[ni] = *(const bhalf8*)&Wsm[(wn + ni * 16 + (lane & 15)) * 32 +
                                          (lane >> 4) * 8];
#pragma unroll
        for (int mi = 0; mi < 4; ++mi)
#pragma unroll
            for (int ni = 0; ni < 4; ++ni)
                acc[mi][ni] = __builtin_amdgcn_mfma_f32_16x16x32_bf16(
                    af[mi], bf[ni], acc[mi][ni], 0, 0, 0);
        __syncthreads();
    }

#pragma unroll
    for (int mi = 0; mi < 4; ++mi)
#pragma unroll
        for (int ni = 0; ni < 4; ++ni) {
            int n = n0 + wn + ni * 16 + (lane & 15);
            float bv = bias[n];
#pragma unroll
            for (int j = 0; j < 4; ++j) {
                int m = m0 + wm + mi * 16 + (lane >> 4) * 4 + j;
                float v = acc[mi][ni][j] + bv;
                if (MODE == 0) {
                    C[(size_t)m * N + n] = v;
                } else {
                    int which = n >> 10;
                    int hh = (n & 1023) >> 6;
                    int dh = n & 63;
                    int b = m >> 10, t = m & 1023;
                    float* dst = (which == 0) ? qb : ((which == 1) ? kb : vb);
                    dst[(((size_t)(b * H + hh)) * T + t) * DH + dh] = v;
                }
            }
        }
}

// ---------------------------------------------------------------------------
// Flash attention fp32 (unchanged)
// ---------------------------------------------------------------------------
__global__ __launch_bounds__(256) void attn_kernel(
    const float* __restrict__ qb, const float* __restrict__ kb,
    const float* __restrict__ vb, float* __restrict__ ctx)
{
    __shared__ float Qs[64][65];
    __shared__ float Ks[64][65];
    __shared__ float Vs[64][65];
    __shared__ float mrow[64], lrow[64], srow[64];
    __shared__ float tred[64][4];

    const int tid = threadIdx.x;
    const int row = tid & 63, seg = tid >> 6;
    const int bx = blockIdx.x;
    const int qblk = bx & 15;
    const int bh = bx >> 4;
    const float* qp = qb + (size_t)bh * T * DH;
    const float* kp = kb + (size_t)bh * T * DH;
    const float* vp = vb + (size_t)bh * T * DH;

#pragma unroll
    for (int i = 0; i < 4; ++i) {
        int lin = tid + i * 256;
        int r = lin >> 4, c4 = lin & 15;
        float4 v = *(const float4*)(qp + (size_t)(qblk * 64 + r) * DH + c4 * 4);
        Qs[r][c4 * 4 + 0] = v.x; Qs[r][c4 * 4 + 1] = v.y;
        Qs[r][c4 * 4 + 2] = v.z; Qs[r][c4 * 4 + 3] = v.w;
    }
    if (tid < 64) { mrow[tid] = -3.0e38f; lrow[tid] = 0.0f; }

    float Oacc[16];
#pragma unroll
    for (int j = 0; j < 16; ++j) Oacc[j] = 0.0f;

    for (int kt = 0; kt < 16; ++kt) {
        __syncthreads();
#pragma unroll
        for (int i = 0; i < 4; ++i) {
            int lin = tid + i * 256;
            int r = lin >> 4, c4 = lin & 15;
            float4 kv = *(const float4*)(kp + (size_t)(kt * 64 + r) * DH + c4 * 4);
            Ks[r][c4 * 4 + 0] = kv.x; Ks[r][c4 * 4 + 1] = kv.y;
            Ks[r][c4 * 4 + 2] = kv.z; Ks[r][c4 * 4 + 3] = kv.w;
            float4 vv = *(const float4*)(vp + (size_t)(kt * 64 + r) * DH + c4 * 4);
            Vs[r][c4 * 4 + 0] = vv.x; Vs[r][c4 * 4 + 1] = vv.y;
            Vs[r][c4 * 4 + 2] = vv.z; Vs[r][c4 * 4 + 3] = vv.w;
        }
        __syncthreads();

        float sacc[16];
#pragma unroll
        for (int j = 0; j < 16; ++j) sacc[j] = 0.0f;
        for (int k = 0; k < 64; ++k) {
            float qv = Qs[row][k];
#pragma unroll
            for (int j = 0; j < 16; ++j) sacc[j] += qv * Ks[seg * 16 + j][k];
        }
        float tmax = -3.0e38f;
#pragma unroll
        for (int j = 0; j < 16; ++j) { sacc[j] *= 0.125f; tmax = fmaxf(tmax, sacc[j]); }
        tred[row][seg] = tmax;
        __syncthreads();
        if (seg == 0) {
            float mt = fmaxf(fmaxf(tred[row][0], tred[row][1]),
                             fmaxf(tred[row][2], tred[row][3]));
            float mo = mrow[row];
            float mn = fmaxf(mo, mt);
            srow[row] = expf(mo - mn);
            mrow[row] = mn;
        }
        __syncthreads();
        float mn = mrow[row], sc = srow[row];
        float psum = 0.0f;
#pragma unroll
        for (int j = 0; j < 16; ++j) {
            float p = expf(sacc[j] - mn);
            Ks[row][seg * 16 + j] = p;
            psum += p;
        }
        tred[row][seg] = psum;
#pragma unroll
        for (int j = 0; j < 16; ++j) Oacc[j] *= sc;
        __syncthreads();
        if (seg == 0)
            lrow[row] = lrow[row] * sc +
                        (tred[row][0] + tred[row][1] + tred[row][2] + tred[row][3]);
        for (int kj = 0; kj < 64; ++kj) {
            float pv = Ks[row][kj];
#pragma unroll
            for (int j = 0; j < 16; ++j) Oacc[j] += pv * Vs[kj][seg * 16 + j];
        }
    }
    __syncthreads();
    float linv = 1.0f / lrow[row];
    int b = bh >> 4, hh = bh & 15;
    int q = qblk * 64 + row;
#pragma unroll
    for (int j = 0; j < 16; ++j)
        ctx[((size_t)(b * T + q)) * D + hh * 64 + seg * 16 + j] = Oacc[j] * linv;
}

// ---------------------------------------------------------------------------
// Persistent GRU: 8 chains x 1 row; each of 512 blocks time-multiplexes TWO
// chains (c, c+4) at the same dim-slice (weights shared -> wpk unchanged).
// While chain c0's flag round-trip propagates through the IC, the block
// computes chain c1 -> per-chain phase period ~= max(sync, 2*work).
// RESIDENCY SAFETY (R12/R14 lesson): 512 blocks need only 2 blocks/CU =
// 8 waves/CU, which holds for ANY VGPR count <= 256 -> no deadlock cliff.
// LDS request 64KB pins exactly 2 blocks/CU. Protocol per chain identical
// to R13 (u64 poll-fused staging, pitch-37 redA, early wave-0 drain+flag).
// Epoch: one `bar` for both chains, incremented after BOTH finish a phase;
// flags posted with value bar+1 to per-chain pages.
// ---------------------------------------------------------------------------
__global__ __launch_bounds__(256, 1) void gru_persistent(
    const float* __restrict__ w_hh, const float* __restrict__ b_hh,
    const float* __restrict__ gate_w,
    const float* __restrict__ gi, const float* __restrict__ ga,
    const float* __restrict__ attn, float* __restrict__ out,
    float* __restrict__ hbuf, float* __restrict__ hpbuf,
    unsigned* __restrict__ flags)
{
    extern __shared__ float lds[];
    float* sh0  = lds;                     // [1024] chain c0 staging
    float* sh1  = lds + 1024;              // [1024] chain c1 staging
    float* redA = lds + 2048;              // [24][37] partial scratch (shared)

    const int tid = threadIdx.x;
    const int pair = blockIdx.x & 3;
    const int pos  = blockIdx.x >> 2;           // 0..127
    const int c0 = pair, c1 = pair + 4;         // the two chains (batch rows)
    const int d0 = pos * DIMS_PER_BLK;
    const int kp = tid & 31, jj = tid >> 5;
    const int d = d0 + jj;

    // ---- resident weights in VGPRs (packed bf16), k = c*128 + kp*4 + {0..3}
    unsigned wpk[4][16];
#pragma unroll
    for (int tt = 0; tt < 4; ++tt) {
        const float* src = (tt < 3) ? (w_hh + ((size_t)(tt * D) + d) * D)
                                    : (gate_w + (size_t)d * (2 * D));
#pragma unroll
        for (int c = 0; c < 8; ++c) {
            float4 v = *(const float4*)(src + c * 128 + kp * 4);
            wpk[tt][c * 2]     = bf16rne(v.x) | (bf16rne(v.y) << 16);
            wpk[tt][c * 2 + 1] = bf16rne(v.z) | (bf16rne(v.w) << 16);
        }
    }

    // finalize-lane constants (tid < 8: one dim each)
    float bfr = 0.0f, bfz = 0.0f, bfn = 0.0f;
    int fd = 0;
    if (tid < 8) {
        fd = d0 + tid;
        bfr = b_hh[fd]; bfz = b_hh[D + fd]; bfn = b_hh[2 * D + fd];
    }

    unsigned* flb0 = flags + (size_t)c0 * NBLK_CHAIN * FLAG_STRIDE;
    unsigned* flb1 = flags + (size_t)c1 * NBLK_CHAIN * FLAG_STRIDE;
    const int srcA = tid >> 2;                  // 0..63
    const int srcB = 64 + srcA;                 // 64..127

    unsigned bar = 0;
    float hpv0 = 0.0f, hpv1 = 0.0f;

// stage one chain's 1024-float vector: u64 j covers dims {2j,2j+1}, owner
// position j>>2; thread handles j in {tid, 256+tid} -> sources {srcA,srcB}.
#define POLL_AND_STAGE(FLB, SRC, SHP)                                         \
    {                                                                         \
        const unsigned long long* p64_ = (const unsigned long long*)(SRC);    \
        while (__hip_atomic_load((FLB) + srcA * FLAG_STRIDE,                  \
                   __ATOMIC_RELAXED, __HIP_MEMORY_SCOPE_AGENT) < bar) {}      \
        unsigned long long r0_ = __hip_atomic_load(p64_ + tid,                \
                __ATOMIC_RELAXED, __HIP_MEMORY_SCOPE_AGENT);                  \
        while (__hip_atomic_load((FLB) + srcB * FLAG_STRIDE,                  \
                   __ATOMIC_RELAXED, __HIP_MEMORY_SCOPE_AGENT) < bar) {}      \
        unsigned long long r1_ = __hip_atomic_load(p64_ + 256 + tid,          \
                __ATOMIC_RELAXED, __HIP_MEMORY_SCOPE_AGENT);                  \
        unsigned long long* sh64_ = (unsigned long long*)(SHP);               \
        sh64_[tid]       = r0_;                                               \
        sh64_[256 + tid] = r1_;                                               \
    }                                                                         \
    __syncthreads();

// phase A segment for one chain
#define SEG_A(FLB, CH, SHP, GIR, GIZ, GIN, HPV)                               \
    {                                                                         \
        POLL_AND_STAGE(FLB, hbuf + (size_t)(CH) * D, SHP)                     \
        float ho_ = 0.0f;                                                     \
        if (tid < 8) ho_ = (SHP)[fd];                                         \
        {                                                                     \
            float ar = 0, az = 0, an = 0;                                     \
            _Pragma("unroll")                                                 \
            for (int c = 0; c < 8; ++c) {                                     \
                float wr0, wr1, wr2, wr3, wz0, wz1, wz2, wz3;                 \
                float wn0, wn1, wn2, wn3;                                     \
                UNPK(wpk[0][c * 2],     wr0, wr1)                             \
                UNPK(wpk[0][c * 2 + 1], wr2, wr3)                             \
                UNPK(wpk[1][c * 2],     wz0, wz1)                             \
                UNPK(wpk[1][c * 2 + 1], wz2, wz3)                             \
                UNPK(wpk[2][c * 2],     wn0, wn1)                             \
                UNPK(wpk[2][c * 2 + 1], wn2, wn3)                             \
                float4 hv = *(const float4*)&(SHP)[c * 128 + kp * 4];         \
                ar += hv.x * wr0 + hv.y * wr1 + hv.z * wr2 + hv.w * wr3;      \
                az += hv.x * wz0 + hv.y * wz1 + hv.z * wz2 + hv.w * wz3;      \
                an += hv.x * wn0 + hv.y * wn1 + hv.z * wn2 + hv.w * wn3;      \
            }                                                                 \
            redA[(jj * 3 + 0) * RED_PITCH + kp] = ar;                         \
            redA[(jj * 3 + 1) * RED_PITCH + kp] = az;                         \
            redA[(jj * 3 + 2) * RED_PITCH + kp] = an;                         \
        }                                                                     \
        __syncthreads();                                                      \
        if (tid < 8) {                                                        \
            int base_ = tid * 3;                                              \
            float sr = 0, sz = 0, sn = 0;                                     \
            _Pragma("unroll")                                                 \
            for (int c = 0; c < 8; ++c) {                                     \
                float4 r4 = *(const float4*)&redA[(base_    ) * RED_PITCH + c * 4]; \
                float4 z4 = *(const float4*)&redA[(base_ + 1) * RED_PITCH + c * 4]; \
                float4 n4 = *(const float4*)&redA[(base_ + 2) * RED_PITCH + c * 4]; \
                sr += (r4.x + r4.y) + (r4.z + r4.w);                          \
                sz += (z4.x + z4.y) + (z4.z + z4.w);                          \
                sn += (n4.x + n4.y) + (n4.z + n4.w);                          \
            }                                                                 \
            float r_ = sigmoidf_((GIR) + sr + bfr);                           \
            float z_ = sigmoidf_((GIZ) + sz + bfz);                           \
            float n_ = tanhf((GIN) + r_ * (sn + bfn));                        \
            (HPV) = (1.0f - z_) * n_ + z_ * ho_;                              \
            __hip_atomic_store(hpbuf + (size_t)(CH) * D + fd, (HPV),          \
                               __ATOMIC_RELAXED, __HIP_MEMORY_SCOPE_AGENT);   \
        }                                                                     \
        if (tid < 64) {                                                       \
            asm volatile("s_waitcnt vmcnt(0)" ::: "memory");                  \
            if (tid == 0)                                                     \
                __hip_atomic_store((FLB) + pos * FLAG_STRIDE, bar + 1,        \
                                   __ATOMIC_RELAXED, __HIP_MEMORY_SCOPE_AGENT); \
        }                                                                     \
    }

// phase B segment for one chain
#define SEG_B(FLB, CH, SHP, GAV, AV, HPV)                                     \
    {                                                                         \
        POLL_AND_STAGE(FLB, hpbuf + (size_t)(CH) * D, SHP)                    \
        {                                                                     \
            float ag = 0;                                                     \
            _Pragma("unroll")                                                 \
            for (int c = 0; c < 8; ++c) {                                     \
                float wg0, wg1, wg2, wg3;                                     \
                UNPK(wpk[3][c * 2],     wg0, wg1)                             \
                UNPK(wpk[3][c * 2 + 1], wg2, wg3)                             \
                float4 hv = *(const float4*)&(SHP)[c * 128 + kp * 4];         \
                ag += hv.x * wg0 + hv.y * wg1 + hv.z * wg2 + hv.w * wg3;      \
            }                                                                 \
            redA[jj * RED_PITCH + kp] = ag;                                   \
        }                                                                     \
        __syncthreads();                                                      \
        if (tid < 8) {                                                        \
            float sg = 0;                                                     \
            _Pragma("unroll")                                                 \
            for (int c = 0; c < 8; ++c) {                                     \
                float4 v = *(const float4*)&redA[tid * RED_PITCH + c * 4];    \
                sg += (v.x + v.y) + (v.z + v.w);                              \
            }                                                                 \
            float g_ = sigmoidf_(sg + (GAV));                                 \
            float hn_ = g_ * (HPV) + (1.0f - g_) * (AV);                      \
            __hip_atomic_store(hbuf + (size_t)(CH) * D + fd, hn_,             \
                               __ATOMIC_RELAXED, __HIP_MEMORY_SCOPE_AGENT);   \
            if (s == NSTEPS - 1)                                              \
                out[((size_t)(CH) * T + t) * D + fd] = hn_;                   \
        }                                                                     \
        if (tid < 64) {                                                       \
            asm volatile("s_waitcnt vmcnt(0)" ::: "memory");                  \
            if (tid == 0)                                                     \
                __hip_atomic_store((FLB) + pos * FLAG_STRIDE, bar + 1,        \
                                   __ATOMIC_RELAXED, __HIP_MEMORY_SCOPE_AGENT); \
        }                                                                     \
    }

    for (int t = 0; t < T; ++t) {
        // per-t inputs for both chains (fin lanes; latency hides under work)
        float giR0 = 0, giZ0 = 0, giN0 = 0, gav0 = 0, av0 = 0;
        float giR1 = 0, giZ1 = 0, giN1 = 0, gav1 = 0, av1 = 0;
        if (tid < 8) {
            const size_t b0 = (size_t)c0 * T + t;
            const float* g0 = gi + b0 * (3 * D);
            giR0 = g0[fd]; giZ0 = g0[D + fd]; giN0 = g0[2 * D + fd];
            gav0 = ga[b0 * D + fd];
            av0  = attn[b0 * D + fd];
            const size_t b1 = (size_t)c1 * T + t;
            const float* g1 = gi + b1 * (3 * D);
            giR1 = g1[fd]; giZ1 = g1[D + fd]; giN1 = g1[2 * D + fd];
            gav1 = ga[b1 * D + fd];
            av1  = attn[b1 * D + fd];
        }
        for (int s = 0; s < NSTEPS; ++s) {
            // phase A: c0 then c1 (c1's compute hides c0's flag latency)
            SEG_A(flb0, c0, sh0, giR0, giZ0, giN0, hpv0)
            SEG_A(flb1, c1, sh1, giR1, giZ1, giN1, hpv1)
            ++bar;
            // phase B: c0 then c1
            SEG_B(flb0, c0, sh0, gav0, av0, hpv0)
            SEG_B(flb1, c1, sh1, gav1, av1, hpv1)
            ++bar;
        }
    }
#undef SEG_A
#undef SEG_B
#undef POLL_AND_STAGE
}

// ---------------------------------------------------------------------------
extern "C" void kernel_launch(void* const* d_in, const int* in_sizes, int n_in,
                              void* d_out, int out_size, void* d_ws, size_t ws_size,
                              hipStream_t stream)
{
    const float* x          = (const float*)d_in[0];
    const float* in_proj_w  = (const float*)d_in[1];
    const float* in_proj_b  = (const float*)d_in[2];
    const float* out_proj_w = (const float*)d_in[3];
    const float* out_proj_b = (const float*)d_in[4];
    const float* w_ih       = (const float*)d_in[5];
    const float* w_hh       = (const float*)d_in[6];
    const float* b_ih       = (const float*)d_in[7];
    const float* b_hh       = (const float*)d_in[8];
    const float* gate_w     = (const float*)d_in[9];
    const float* gate_b     = (const float*)d_in[10];
    float* out = (float*)d_out;

    float* ws = (float*)d_ws;
    const size_t S1 = (size_t)B * H * T * DH;   // 8,388,608 floats
    float* qb   = ws;
    float* kb   = ws + S1;
    float* vb   = ws + 2 * S1;
    float* ctx  = ws + 3 * S1;
    float* attn = ws + 4 * S1;
    float* ga   = ws + 5 * S1;
    float* gi   = ws;                           // overlaps q/k/v
    float* hbuf  = ws + 6 * S1;
    float* hpbuf = hbuf + B * D;
    unsigned* flags = (unsigned*)(hpbuf + B * D);  // 8 chains *128 flags *64B

    dim3 blk(256);

    // 1. qkv = x @ in_proj_w^T (bf16 MFMA) -> scatter q/k/v
    gemm_mfma<1><<<dim3(64, 24), blk, 0, stream>>>(
        x, in_proj_w, in_proj_b, nullptr, B * T, 3 * D, D, D, 0, qb, kb, vb);
    // 2. attention (fp32)
    attn_kernel<<<dim3(2048), blk, 0, stream>>>(qb, kb, vb, ctx);
    // 3. out_proj (bf16 MFMA)
    gemm_mfma<0><<<dim3(64, 8), blk, 0, stream>>>(
        ctx, out_proj_w, out_proj_b, attn, B * T, D, D, D, 0,
        nullptr, nullptr, nullptr);
    // 4. ga = attn @ gate_w[:, D:]^T (bf16 MFMA)
    gemm_mfma<0><<<dim3(64, 8), blk, 0, stream>>>(
        attn, gate_w, gate_b, ga, B * T, D, D, 2 * D, D,
        nullptr, nullptr, nullptr);
    // 5. gi = x @ w_ih^T (bf16 MFMA)
    gemm_mfma<0><<<dim3(64, 24), blk, 0, stream>>>(
        x, w_ih, b_ih, gi, B * T, 3 * D, D, D, 0,
        nullptr, nullptr, nullptr);

    // zero h, hp, and all 8 flag pages every launch (graph-replay safe)
    hipMemsetAsync(hbuf, 0,
                   (2 * (size_t)B * D) * sizeof(float) +
                   (size_t)NCHAIN * NBLK_CHAIN * FLAG_STRIDE * sizeof(unsigned),
                   stream);

    // LDS need ~11.7 KB; request 64 KB -> exactly 2 blocks/CU. 512 blocks
    // resident for ANY VGPR <= 256 (no deadlock cliff -- R14 lesson).
    const int LDS_BYTES = 65536;
    static bool attr_done = false;
    if (!attr_done) {
        hipFuncSetAttribute((const void*)gru_persistent,
                            hipFuncAttributeMaxDynamicSharedMemorySize, LDS_BYTES);
        attr_done = true;
    }
    gru_persistent<<<dim3(NPAIR * NBLK_CHAIN), blk, LDS_BYTES, stream>>>(
        w_hh, b_hh, gate_w, gi, ga, attn, out, hbuf, hpbuf, flags);
}

// Round 16
// 27027.533 us; speedup vs baseline: 1.3313x; 1.3313x over previous
//
#include <hip/hip_runtime.h>
#include <hip/hip_bf16.h>
#include <math.h>
#include <stdint.h>

#define B 8
#define T 1024
#define D 1024
#define H 16
#define DH 64
#define NSTEPS 4

#define NCHAIN 4            // batch split into 4 independent chains of 2 rows
#define ROWS_PER_CHAIN 2
#define NBLK_CHAIN 128      // blocks per chain (512 total, 2 per CU)
#define DIMS_PER_BLK 8      // 128 * 8 = 1024 dims

#define FLAG_STRIDE 16      // flags 64B apart (own cache line each)
#define RED_PITCH 37        // redA pitch (coprime to 32 -> conflict-free cols)

typedef __attribute__((ext_vector_type(8))) short bhalf8;
typedef __attribute__((ext_vector_type(4))) float f32x4;

__device__ __forceinline__ float sigmoidf_(float x) { return 1.0f / (1.0f + expf(-x)); }

// bf16 round-to-nearest-even, returned in low 16 bits
__device__ __forceinline__ unsigned bf16rne(float f) {
    unsigned x = __float_as_uint(f);
    return (x + 0x7FFFu + ((x >> 16) & 1u)) >> 16;
}
// unpack u32 = bf0 | bf1<<16 into two f32
#define UNPK(u, f0, f1)                                                       \
    { f0 = __uint_as_float((u) << 16); f1 = __uint_as_float((u) & 0xFFFF0000u); }

// ---------------------------------------------------------------------------
// bf16 MFMA GEMM (proven R12/R13): C[M,N] = A[M,K] @ W[N,K]^T + bias[N],
// fp32 in/out, inline fp32->bf16 staging. 128x128 tile, BK=32, 4 waves.
// MODE 0: C[m*N+n]; MODE 1: qkv scatter to q/k/v [B*H, T, DH].
// ---------------------------------------------------------------------------
template <int MODE>
__global__ __launch_bounds__(256) void gemm_mfma(
    const float* __restrict__ A, const float* __restrict__ W,
    const float* __restrict__ bias, float* __restrict__ C,
    int M, int N, int K, int ldw, int koff,
    float* __restrict__ qb, float* __restrict__ kb, float* __restrict__ vb)
{
    __shared__ unsigned short Asm[128 * 32];
    __shared__ unsigned short Wsm[128 * 32];
    const int tid = threadIdx.x;
    const int m0 = blockIdx.x * 128, n0 = blockIdx.y * 128;
    const int lane = tid & 63, wave = tid >> 6;
    const int wm = (wave >> 1) * 64, wn = (wave & 1) * 64;
    const int sr = tid >> 1, sk = (tid & 1) * 16;

    f32x4 acc[4][4] = {};

    for (int k0 = 0; k0 < K; k0 += 32) {
        {
            const float* s = A + (size_t)(m0 + sr) * K + k0 + sk;
            float4 a0 = *(const float4*)(s);
            float4 a1 = *(const float4*)(s + 4);
            float4 a2 = *(const float4*)(s + 8);
            float4 a3 = *(const float4*)(s + 12);
            uint4 p0, p1;
            p0.x = bf16rne(a0.x) | (bf16rne(a0.y) << 16);
            p0.y = bf16rne(a0.z) | (bf16rne(a0.w) << 16);
            p0.z = bf16rne(a1.x) | (bf16rne(a1.y) << 16);
            p0.w = bf16rne(a1.z) | (bf16rne(a1.w) << 16);
            p1.x = bf16rne(a2.x) | (bf16rne(a2.y) << 16);
            p1.y = bf16rne(a2.z) | (bf16rne(a2.w) << 16);
            p1.z = bf16rne(a3.x) | (bf16rne(a3.y) << 16);
            p1.w = bf16rne(a3.z) | (bf16rne(a3.w) << 16);
            *(uint4*)&Asm[sr * 32 + sk]     = p0;
            *(uint4*)&Asm[sr * 32 + sk + 8] = p1;
        }
        {
            const float* s = W + (size_t)(n0 + sr) * ldw + koff + k0 + sk;
            float4 a0 = *(const float4*)(s);
            float4 a1 = *(const float4*)(s + 4);
            float4 a2 = *(const float4*)(s + 8);
            float4 a3 = *(const float4*)(s + 12);
            uint4 p0, p1;
            p0.x = bf16rne(a0.x) | (bf16rne(a0.y) << 16);
            p0.y = bf16rne(a0.z) | (bf16rne(a0.w) << 16);
            p0.z = bf16rne(a1.x) | (bf16rne(a1.y) << 16);
            p0.w = bf16rne(a1.z) | (bf16rne(a1.w) << 16);
            p1.x = bf16rne(a2.x) | (bf16rne(a2.y) << 16);
            p1.y = bf16rne(a2.z) | (bf16rne(a2.w) << 16);
            p1.z = bf16rne(a3.x) | (bf16rne(a3.y) << 16);
            p1.w = bf16rne(a3.z) | (bf16rne(a3.w) << 16);
            *(uint4*)&Wsm[sr * 32 + sk]     = p0;
            *(uint4*)&Wsm[sr * 32 + sk + 8] = p1;
        }
        __syncthreads();

        bhalf8 af[4], bf[4];
#pragma unroll
        for (int mi = 0; mi < 4; ++mi)
            af[mi] = *(const bhalf8*)&Asm[(wm + mi * 16 + (lane & 15)) * 32 +
                                          (lane >> 4) * 8];
#pragma unroll
        for (int ni = 0; ni < 4; ++ni)
            bf[ni] = *(const bhalf8*)&Wsm[(wn + ni * 16 + (lane & 15)) * 32 +
                                          (lane >> 4) * 8];
#pragma unroll
        for (int mi = 0; mi < 4; ++mi)
#pragma unroll
            for (int ni = 0; ni < 4; ++ni)
                acc[mi][ni] = __builtin_amdgcn_mfma_f32_16x16x32_bf16(
                    af[mi], bf[ni], acc[mi][ni], 0, 0, 0);
        __syncthreads();
    }

#pragma unroll
    for (int mi = 0; mi < 4; ++mi)
#pragma unroll
        for (int ni = 0; ni < 4; ++ni) {
            int n = n0 + wn + ni * 16 + (lane & 15);
            float bv = bias[n];
#pragma unroll
            for (int j = 0; j < 4; ++j) {
                int m = m0 + wm + mi * 16 + (lane >> 4) * 4 + j;
                float v = acc[mi][ni][j] + bv;
                if (MODE == 0) {
                    C[(size_t)m * N + n] = v;
                } else {
                    int which = n >> 10;
                    int hh = (n & 1023) >> 6;
                    int dh = n & 63;
                    int b = m >> 10, t = m & 1023;
                    float* dst = (which == 0) ? qb : ((which == 1) ? kb : vb);
                    dst[(((size_t)(b * H + hh)) * T + t) * DH + dh] = v;
                }
            }
        }
}

// ---------------------------------------------------------------------------
// Flash attention fp32 (unchanged)
// ---------------------------------------------------------------------------
__global__ __launch_bounds__(256) void attn_kernel(
    const float* __restrict__ qb, const float* __restrict__ kb,
    const float* __restrict__ vb, float* __restrict__ ctx)
{
    __shared__ float Qs[64][65];
    __shared__ float Ks[64][65];
    __shared__ float Vs[64][65];
    __shared__ float mrow[64], lrow[64], srow[64];
    __shared__ float tred[64][4];

    const int tid = threadIdx.x;
    const int row = tid & 63, seg = tid >> 6;
    const int bx = blockIdx.x;
    const int qblk = bx & 15;
    const int bh = bx >> 4;
    const float* qp = qb + (size_t)bh * T * DH;
    const float* kp = kb + (size_t)bh * T * DH;
    const float* vp = vb + (size_t)bh * T * DH;

#pragma unroll
    for (int i = 0; i < 4; ++i) {
        int lin = tid + i * 256;
        int r = lin >> 4, c4 = lin & 15;
        float4 v = *(const float4*)(qp + (size_t)(qblk * 64 + r) * DH + c4 * 4);
        Qs[r][c4 * 4 + 0] = v.x; Qs[r][c4 * 4 + 1] = v.y;
        Qs[r][c4 * 4 + 2] = v.z; Qs[r][c4 * 4 + 3] = v.w;
    }
    if (tid < 64) { mrow[tid] = -3.0e38f; lrow[tid] = 0.0f; }

    float Oacc[16];
#pragma unroll
    for (int j = 0; j < 16; ++j) Oacc[j] = 0.0f;

    for (int kt = 0; kt < 16; ++kt) {
        __syncthreads();
#pragma unroll
        for (int i = 0; i < 4; ++i) {
            int lin = tid + i * 256;
            int r = lin >> 4, c4 = lin & 15;
            float4 kv = *(const float4*)(kp + (size_t)(kt * 64 + r) * DH + c4 * 4);
            Ks[r][c4 * 4 + 0] = kv.x; Ks[r][c4 * 4 + 1] = kv.y;
            Ks[r][c4 * 4 + 2] = kv.z; Ks[r][c4 * 4 + 3] = kv.w;
            float4 vv = *(const float4*)(vp + (size_t)(kt * 64 + r) * DH + c4 * 4);
            Vs[r][c4 * 4 + 0] = vv.x; Vs[r][c4 * 4 + 1] = vv.y;
            Vs[r][c4 * 4 + 2] = vv.z; Vs[r][c4 * 4 + 3] = vv.w;
        }
        __syncthreads();

        float sacc[16];
#pragma unroll
        for (int j = 0; j < 16; ++j) sacc[j] = 0.0f;
        for (int k = 0; k < 64; ++k) {
            float qv = Qs[row][k];
#pragma unroll
            for (int j = 0; j < 16; ++j) sacc[j] += qv * Ks[seg * 16 + j][k];
        }
        float tmax = -3.0e38f;
#pragma unroll
        for (int j = 0; j < 16; ++j) { sacc[j] *= 0.125f; tmax = fmaxf(tmax, sacc[j]); }
        tred[row][seg] = tmax;
        __syncthreads();
        if (seg == 0) {
            float mt = fmaxf(fmaxf(tred[row][0], tred[row][1]),
                             fmaxf(tred[row][2], tred[row][3]));
            float mo = mrow[row];
            float mn = fmaxf(mo, mt);
            srow[row] = expf(mo - mn);
            mrow[row] = mn;
        }
        __syncthreads();
        float mn = mrow[row], sc = srow[row];
        float psum = 0.0f;
#pragma unroll
        for (int j = 0; j < 16; ++j) {
            float p = expf(sacc[j] - mn);
            Ks[row][seg * 16 + j] = p;
            psum += p;
        }
        tred[row][seg] = psum;
#pragma unroll
        for (int j = 0; j < 16; ++j) Oacc[j] *= sc;
        __syncthreads();
        if (seg == 0)
            lrow[row] = lrow[row] * sc +
                        (tred[row][0] + tred[row][1] + tred[row][2] + tred[row][3]);
        for (int kj = 0; kj < 64; ++kj) {
            float pv = Ks[row][kj];
#pragma unroll
            for (int j = 0; j < 16; ++j) Oacc[j] += pv * Vs[kj][seg * 16 + j];
        }
    }
    __syncthreads();
    float linv = 1.0f / lrow[row];
    int b = bh >> 4, hh = bh & 15;
    int q = qblk * 64 + row;
#pragma unroll
    for (int j = 0; j < 16; ++j)
        ctx[((size_t)(b * T + q)) * D + hh * 64 + seg * 16 + j] = Oacc[j] * linv;
}

// ---------------------------------------------------------------------------
// Persistent GRU recurrence: R13's proven configuration VERBATIM (best
// measured: 26.35 ms). 4 chains x 2 rows, 512 blocks, 2 blocks/CU (64KB LDS
// request forces it; residency holds for ANY VGPR <= 256 -> no cliff).
// VGPR-resident bf16 weights (124 VGPR measured). Protocol: distributed
// per-block epoch flags + u64 poll-fused staging (2 sources/thread),
// pitch-37 redA, 16 fin lanes, early wave-0 drain+flag, pre-bar2 ho read.
// Sync floor ~2.5us/phase = IC coherence-point RTT; 8192 serial exchanges
// are structural (both matvecs need the full cross-block vector).
// ---------------------------------------------------------------------------
__global__ __launch_bounds__(256, 1) void gru_persistent(
    const float* __restrict__ w_hh, const float* __restrict__ b_hh,
    const float* __restrict__ gate_w,
    const float* __restrict__ gi, const float* __restrict__ ga,
    const float* __restrict__ attn, float* __restrict__ out,
    float* __restrict__ hbuf, float* __restrict__ hpbuf,
    unsigned* __restrict__ flags)
{
    extern __shared__ float lds[];
    float* sh   = lds;                     // [2][1024] staged h or hp
    float* redA = lds + 2048;              // [48][37] partial scratch

    const int tid = threadIdx.x;
    const int chain = blockIdx.x & 3;
    const int pos = blockIdx.x >> 2;            // 0..127
    const int d0 = pos * DIMS_PER_BLK;
    const int kp = tid & 31, jj = tid >> 5;
    const int d = d0 + jj;

    // ---- resident weights in VGPRs (packed bf16), k = c*128 + kp*4 + {0..3}
    unsigned wpk[4][16];
#pragma unroll
    for (int tt = 0; tt < 4; ++tt) {
        const float* src = (tt < 3) ? (w_hh + ((size_t)(tt * D) + d) * D)
                                    : (gate_w + (size_t)d * (2 * D));
#pragma unroll
        for (int c = 0; c < 8; ++c) {
            float4 v = *(const float4*)(src + c * 128 + kp * 4);
            wpk[tt][c * 2]     = bf16rne(v.x) | (bf16rne(v.y) << 16);
            wpk[tt][c * 2 + 1] = bf16rne(v.z) | (bf16rne(v.w) << 16);
        }
    }

    // finalize-thread constants (tid < 16: jj2 = tid>>1, bl = tid&1)
    float bfr = 0.0f, bfz = 0.0f, bfn = 0.0f;
    int fd = 0, fbg = 0;
    if (tid < 16) {
        int jj2 = tid >> 1, bl = tid & 1;
        fd = d0 + jj2;
        fbg = chain * ROWS_PER_CHAIN + bl;
        bfr = b_hh[fd]; bfz = b_hh[D + fd]; bfn = b_hh[2 * D + fd];
    }

    unsigned* flagbase = flags + (size_t)chain * NBLK_CHAIN * FLAG_STRIDE;
    const int srcA = tid >> 2;                  // 0..63
    const int srcB = srcA + 64;                 // 64..127
    const float* hsrc  = hbuf  + (size_t)chain * ROWS_PER_CHAIN * D;
    const float* hpsrc = hpbuf + (size_t)chain * ROWS_PER_CHAIN * D;

    unsigned bar = 0;                           // completed-phase epoch
    float hpv = 0.0f;                           // finalize threads only

#define POLL_AND_STAGE(SRC)                                                   \
    {                                                                         \
        const unsigned long long* p64_ = (const unsigned long long*)(SRC);    \
        while (__hip_atomic_load(flagbase + srcA * FLAG_STRIDE,               \
                   __ATOMIC_RELAXED, __HIP_MEMORY_SCOPE_AGENT) < bar) {}      \
        unsigned long long r0_ = __hip_atomic_load(p64_ + tid,                \
                __ATOMIC_RELAXED, __HIP_MEMORY_SCOPE_AGENT);                  \
        unsigned long long r2_ = __hip_atomic_load(p64_ + 512 + tid,          \
                __ATOMIC_RELAXED, __HIP_MEMORY_SCOPE_AGENT);                  \
        while (__hip_atomic_load(flagbase + srcB * FLAG_STRIDE,               \
                   __ATOMIC_RELAXED, __HIP_MEMORY_SCOPE_AGENT) < bar) {}      \
        unsigned long long r1_ = __hip_atomic_load(p64_ + 256 + tid,          \
                __ATOMIC_RELAXED, __HIP_MEMORY_SCOPE_AGENT);                  \
        unsigned long long r3_ = __hip_atomic_load(p64_ + 768 + tid,          \
                __ATOMIC_RELAXED, __HIP_MEMORY_SCOPE_AGENT);                  \
        unsigned long long* sh64_ = (unsigned long long*)sh;                  \
        sh64_[tid]       = r0_;                                               \
        sh64_[256 + tid] = r1_;                                               \
        sh64_[512 + tid] = r2_;                                               \
        sh64_[768 + tid] = r3_;                                               \
    }                                                                         \
    __syncthreads();

    for (int t = 0; t < T; ++t) {
        float giR = 0, giZ = 0, giN = 0, gav = 0, av = 0;
        if (tid < 16) {
            const size_t base = (size_t)fbg * T + t;
            const float* gib = gi + base * (3 * D);
            giR = gib[fd]; giZ = gib[D + fd]; giN = gib[2 * D + fd];
            gav = ga[base * D + fd];
            av  = attn[base * D + fd];
        }
        for (int s = 0; s < NSTEPS; ++s) {
            // ================= phase A: gh = h @ w_hh^T =================
            POLL_AND_STAGE(hsrc)
            float ho = 0.0f;
            if (tid < 16) ho = sh[(tid & 1) * 1024 + fd];   // pre-bar2 read
            {
                float ar[2] = {0, 0}, az[2] = {0, 0}, an[2] = {0, 0};
#pragma unroll
                for (int c = 0; c < 8; ++c) {
                    float wr0, wr1, wr2, wr3, wz0, wz1, wz2, wz3;
                    float wn0, wn1, wn2, wn3;
                    UNPK(wpk[0][c * 2],     wr0, wr1)
                    UNPK(wpk[0][c * 2 + 1], wr2, wr3)
                    UNPK(wpk[1][c * 2],     wz0, wz1)
                    UNPK(wpk[1][c * 2 + 1], wz2, wz3)
                    UNPK(wpk[2][c * 2],     wn0, wn1)
                    UNPK(wpk[2][c * 2 + 1], wn2, wn3)
                    const int ha = c * 128 + kp * 4;
#pragma unroll
                    for (int bl = 0; bl < 2; ++bl) {
                        float4 hv = *(const float4*)&sh[bl * 1024 + ha];
                        ar[bl] += hv.x * wr0 + hv.y * wr1 + hv.z * wr2 + hv.w * wr3;
                        az[bl] += hv.x * wz0 + hv.y * wz1 + hv.z * wz2 + hv.w * wz3;
                        an[bl] += hv.x * wn0 + hv.y * wn1 + hv.z * wn2 + hv.w * wn3;
                    }
                }
#pragma unroll
                for (int bl = 0; bl < 2; ++bl) {
                    redA[(jj * 6 + 0 + bl) * RED_PITCH + kp] = ar[bl];
                    redA[(jj * 6 + 2 + bl) * RED_PITCH + kp] = az[bl];
                    redA[(jj * 6 + 4 + bl) * RED_PITCH + kp] = an[bl];
                }
            }
            __syncthreads();                    // bar2: redA ready, sh free
            if (tid < 16) {
                int base = (tid >> 1) * 6 + (tid & 1);
                float sr = 0, sz = 0, sn = 0;
#pragma unroll
                for (int c = 0; c < 8; ++c) {
                    float4 r4 = *(const float4*)&redA[(base    ) * RED_PITCH + c * 4];
                    float4 z4 = *(const float4*)&redA[(base + 2) * RED_PITCH + c * 4];
                    float4 n4 = *(const float4*)&redA[(base + 4) * RED_PITCH + c * 4];
                    sr += (r4.x + r4.y) + (r4.z + r4.w);
                    sz += (z4.x + z4.y) + (z4.z + z4.w);
                    sn += (n4.x + n4.y) + (n4.z + n4.w);
                }
                float r_ = sigmoidf_(giR + sr + bfr);
                float z_ = sigmoidf_(giZ + sz + bfz);
                float n_ = tanhf(giN + r_ * (sn + bfn));
                hpv = (1.0f - z_) * n_ + z_ * ho;
                __hip_atomic_store(hpbuf + (size_t)fbg * D + fd, hpv,
                                   __ATOMIC_RELAXED, __HIP_MEMORY_SCOPE_AGENT);
            }
            ++bar;
            if (tid < 64) {                     // wave 0 only: drain + flag
                asm volatile("s_waitcnt vmcnt(0)" ::: "memory");
                if (tid == 0)
                    __hip_atomic_store(flagbase + pos * FLAG_STRIDE, bar,
                                       __ATOMIC_RELAXED, __HIP_MEMORY_SCOPE_AGENT);
            }

            // ============ phase B: g = sigmoid(hp @ gwL^T + ga) ==========
            POLL_AND_STAGE(hpsrc)
            {
                float ag[2] = {0, 0};
#pragma unroll
                for (int c = 0; c < 8; ++c) {
                    float wg0, wg1, wg2, wg3;
                    UNPK(wpk[3][c * 2],     wg0, wg1)
                    UNPK(wpk[3][c * 2 + 1], wg2, wg3)
                    const int ha = c * 128 + kp * 4;
#pragma unroll
                    for (int bl = 0; bl < 2; ++bl) {
                        float4 hv = *(const float4*)&sh[bl * 1024 + ha];
                        ag[bl] += hv.x * wg0 + hv.y * wg1 + hv.z * wg2 + hv.w * wg3;
                    }
                }
#pragma unroll
                for (int bl = 0; bl < 2; ++bl)
                    redA[(jj * 2 + bl) * RED_PITCH + kp] = ag[bl];
            }
            __syncthreads();                    // bar2
            float hn = 0.0f;
            if (tid < 16) {
                float sg = 0;
#pragma unroll
                for (int c = 0; c < 8; ++c) {
                    float4 v = *(const float4*)&redA[tid * RED_PITCH + c * 4];
                    sg += (v.x + v.y) + (v.z + v.w);
                }
                float g = sigmoidf_(sg + gav);
                hn = g * hpv + (1.0f - g) * av;
                __hip_atomic_store(hbuf + (size_t)fbg * D + fd, hn,
                                   __ATOMIC_RELAXED, __HIP_MEMORY_SCOPE_AGENT);
            }
            ++bar;
            if (tid < 64) {                     // wave 0 only: drain + flag
                asm volatile("s_waitcnt vmcnt(0)" ::: "memory");
                if (tid == 0)
                    __hip_atomic_store(flagbase + pos * FLAG_STRIDE, bar,
                                       __ATOMIC_RELAXED, __HIP_MEMORY_SCOPE_AGENT);
            }
            if (tid < 16 && s == NSTEPS - 1)    // off the handshake path
                out[((size_t)fbg * T + t) * D + fd] = hn;
        }
    }
#undef POLL_AND_STAGE
}

// ---------------------------------------------------------------------------
extern "C" void kernel_launch(void* const* d_in, const int* in_sizes, int n_in,
                              void* d_out, int out_size, void* d_ws, size_t ws_size,
                              hipStream_t stream)
{
    const float* x          = (const float*)d_in[0];
    const float* in_proj_w  = (const float*)d_in[1];
    const float* in_proj_b  = (const float*)d_in[2];
    const float* out_proj_w = (const float*)d_in[3];
    const float* out_proj_b = (const float*)d_in[4];
    const float* w_ih       = (const float*)d_in[5];
    const float* w_hh       = (const float*)d_in[6];
    const float* b_ih       = (const float*)d_in[7];
    const float* b_hh       = (const float*)d_in[8];
    const float* gate_w     = (const float*)d_in[9];
    const float* gate_b     = (const float*)d_in[10];
    float* out = (float*)d_out;

    float* ws = (float*)d_ws;
    const size_t S1 = (size_t)B * H * T * DH;   // 8,388,608 floats
    float* qb   = ws;
    float* kb   = ws + S1;
    float* vb   = ws + 2 * S1;
    float* ctx  = ws + 3 * S1;
    float* attn = ws + 4 * S1;
    float* ga   = ws + 5 * S1;
    float* gi   = ws;                           // overlaps q/k/v
    float* hbuf  = ws + 6 * S1;
    float* hpbuf = hbuf + B * D;
    unsigned* flags = (unsigned*)(hpbuf + B * D);  // 4 chains *128 flags *64B

    dim3 blk(256);

    // 1. qkv = x @ in_proj_w^T (bf16 MFMA) -> scatter q/k/v
    gemm_mfma<1><<<dim3(64, 24), blk, 0, stream>>>(
        x, in_proj_w, in_proj_b, nullptr, B * T, 3 * D, D, D, 0, qb, kb, vb);
    // 2. attention (fp32)
    attn_kernel<<<dim3(2048), blk, 0, stream>>>(qb, kb, vb, ctx);
    // 3. out_proj (bf16 MFMA)
    gemm_mfma<0><<<dim3(64, 8), blk, 0, stream>>>(
        ctx, out_proj_w, out_proj_b, attn, B * T, D, D, D, 0,
        nullptr, nullptr, nullptr);
    // 4. ga = attn @ gate_w[:, D:]^T (bf16 MFMA)
    gemm_mfma<0><<<dim3(64, 8), blk, 0, stream>>>(
        attn, gate_w, gate_b, ga, B * T, D, D, 2 * D, D,
        nullptr, nullptr, nullptr);
    // 5. gi = x @ w_ih^T (bf16 MFMA; q/k/v dead by now)
    gemm_mfma<0><<<dim3(64, 24), blk, 0, stream>>>(
        x, w_ih, b_ih, gi, B * T, 3 * D, D, D, 0,
        nullptr, nullptr, nullptr);

    // zero h, hp, and flags every launch (graph-replay deterministic)
    hipMemsetAsync(hbuf, 0,
                   (2 * (size_t)B * D) * sizeof(float) +
                   (size_t)NCHAIN * NBLK_CHAIN * FLAG_STRIDE * sizeof(unsigned),
                   stream);

    // actual LDS need ~15.3 KB; request 64 KB so exactly 2 blocks/CU
    // (3 x 64 KB > 160 KB) -> all 512 blocks resident (256 CUs x 2).
    const int LDS_BYTES = 65536;
    static bool attr_done = false;
    if (!attr_done) {
        hipFuncSetAttribute((const void*)gru_persistent,
                            hipFuncAttributeMaxDynamicSharedMemorySize, LDS_BYTES);
        attr_done = true;
    }
    gru_persistent<<<dim3(NCHAIN * NBLK_CHAIN), blk, LDS_BYTES, stream>>>(
        w_hh, b_hh, gate_w, gi, ga, attn, out, hbuf, hpbuf, flags);
}